// Round 10
// baseline (21173.096 us; speedup 1.0000x reference)
//
#include <hip/hip_runtime.h>

typedef float f32x4 __attribute__((ext_vector_type(4)));

#define NXg   512
#define NYg   512
#define NTt   400
#define DIMg  520
#define NCELL (DIMg*DIMg)
#define DTc   0.001f
#define Hc    10.0f

#define C0f (-205.0f/72.0f)
#define C1f (8.0f/5.0f)
#define C2f (-1.0f/5.0f)
#define C3f (8.0f/315.0f)
#define C4f (-1.0f/560.0f)

// One-time per call: zero F0/F1 fields + flags, build scale[] (mask folded:
// 0 on the 4-wide pad ring), params: ints[0..2]=srcY,srcX,recY; [4+t]=w[t]*amp.
__global__ void time2d_init(const float* __restrict__ vel,
                            const float* __restrict__ w,
                            const int* __restrict__ sxp,
                            const int* __restrict__ syp,
                            const int* __restrict__ ryp,
                            float* __restrict__ F01,     // 2*NCELL
                            float* __restrict__ scale,
                            float* __restrict__ params,
                            int*   __restrict__ flags) {
    int idx = blockIdx.x * blockDim.x + threadIdx.x;
    if (idx < NCELL) {
        int y = idx / DIMg;
        int x = idx - y * DIMg;
        float s = 0.0f;
        if (y >= 4 && y < 516 && x >= 4 && x < 516) {
            // scale[y][x] = (vel[x-4][y-4]*DT)^2 / H^2   (transposed pad)
            float v = vel[(x - 4) * NYg + (y - 4)] * DTc;
            s = v * v / (Hc * Hc);
        }
        scale[idx] = s;
    }
    for (int i = idx; i < 2 * NCELL; i += gridDim.x * blockDim.x)
        F01[i] = 0.0f;
    if (idx < NTt) {
        const int sx = *sxp, sy = *syp;
        const float va = vel[sx * NYg + sy] * DTc;
        params[4 + idx] = w[idx] * (va * va);
    }
    if (idx < 512) flags[idx] = 0;
    if (idx == 0) {
        int* pi = (int*)params;
        pi[0] = *syp + 4;   // srcY
        pi[1] = *sxp + 4;   // srcX
        pi[2] = *ryp + 4;   // recY
    }
}

// Persistent dataflow kernel, GLOBAL<->GLOBAL (no LDS residency).
// 512 blocks (16x32), 128 threads, block owns a 32x16 interior tile
// (1 quad x 1 row per thread). Per step: 4 poller threads spin on the <=4
// axis neighbors' flags (atomicOr readback, device-scope), barrier,
// __threadfence (acquire); plain f32x4 loads of the 9-quad y-window + 2
// x-quads from the parity source field; compute; plain store of own quad to
// the destination field; __threadfence (release), barrier, atomicExch flag.
// Flag wait is symmetric: covers RAW (neighbor wrote u(t)) and WAR
// (neighbor finished reading u(t-1) before we overwrite that buffer).
__launch_bounds__(128)
__global__ void time2d_persist(const float* __restrict__ scale,
                               const float* __restrict__ params,
                               float* __restrict__ F0,
                               float* __restrict__ F1,
                               int*   flags,
                               float* __restrict__ out)
{
    const int tid = threadIdx.x;
    const int bx = blockIdx.x, by = blockIdx.y;     // 16 x 32
    const int bid = by * 16 + bx;
    const int qc = tid & 7, r = tid >> 3;           // quad-col 0..7, row 0..15
    const int gxq = 4 + bx * 32 + qc * 4;
    const int gy  = 4 + by * 16 + r;
    const int myofs = gy * DIMg + gxq;

    const int* pi = (const int*)params;
    const int srcY = pi[0], srcX = pi[1], recY = pi[2];
    const float* wamp = params + 4;

    const f32x4 scq = *(const f32x4*)&scale[myofs];
    f32x4 prevq = (f32x4)0.0f;
    int srcJ = -1;
    if (gy == srcY && (unsigned)(srcX - gxq) < 4u) srcJ = srcX - gxq;
    const bool recRow = (gy == recY);

    // Poller assignment: tid0=W, tid1=E, tid2=N, tid3=S; missing -> self
    // (own flag == t at step t, passes immediately).
    int nbid = bid;
    if (tid == 0 && bx > 0)  nbid = bid - 1;
    if (tid == 1 && bx < 15) nbid = bid + 1;
    if (tid == 2 && by > 0)  nbid = bid - 16;
    if (tid == 3 && by < 31) nbid = bid + 16;

    for (int t = 0; t < NTt; ++t) {
        // 1. wait: neighbors completed >= t steps
        if (t > 0) {
            if (tid < 4)
                while (atomicOr(&flags[nbid], 0) < t)
                    __builtin_amdgcn_s_sleep(2);
            __syncthreads();
            __threadfence();          // acquire: invalidate caches
        }
        const float* __restrict__ Fs = (t & 1) ? F1 : F0;   // u(t)
        float*       __restrict__ Fd = (t & 1) ? F0 : F1;   // u(t+1)

        // 2. load window (plain vector loads; pad ring stays 0)
        f32x4 win[9];
        #pragma unroll
        for (int m = 0; m < 9; ++m)
            win[m] = *(const f32x4*)&Fs[myofs + (m - 4) * DIMg];
        const f32x4 lq = *(const f32x4*)&Fs[myofs - 4];
        const f32x4 rq = *(const f32x4*)&Fs[myofs + 4];

        // 3. compute
        float h[12];
        #pragma unroll
        for (int j = 0; j < 4; ++j) {
            h[j] = lq[j]; h[4 + j] = win[4][j]; h[8 + j] = rq[j];
        }
        f32x4 nv;
        const float wv = wamp[t];
        #pragma unroll
        for (int j = 0; j < 4; ++j) {
            const float ctr = h[4 + j];
            const float lap = 2.0f * C0f * ctr
              + C1f * (win[3][j] + win[5][j] + h[3 + j] + h[5 + j])
              + C2f * (win[2][j] + win[6][j] + h[2 + j] + h[6 + j])
              + C3f * (win[1][j] + win[7][j] + h[1 + j] + h[7 + j])
              + C4f * (win[0][j] + win[8][j] + h[0 + j] + h[8 + j]);
            float nvj = 2.0f * ctr - prevq[j] + scq[j] * lap;
            if (srcJ == j) nvj += wv;
            nv[j] = nvj;
        }
        prevq = win[4];

        // 4. store own quad + receiver row
        *(f32x4*)&Fd[myofs] = nv;
        if (recRow)
            *(f32x4*)&out[(size_t)t * NXg + (gxq - 4)] = nv;

        // 5. publish
        if (t < NTt - 1) {
            __threadfence();          // release: drain stores
            __syncthreads();
            if (tid == 0) atomicExch(&flags[bid], t + 1);
        }
    }
}

extern "C" void kernel_launch(void* const* d_in, const int* in_sizes, int n_in,
                              void* d_out, int out_size, void* d_ws, size_t ws_size,
                              hipStream_t stream) {
    const float* vel = (const float*)d_in[0];
    const float* w   = (const float*)d_in[1];
    const int*   sx  = (const int*)d_in[2];
    const int*   sy  = (const int*)d_in[3];
    const int*   ry  = (const int*)d_in[4];
    float* out = (float*)d_out;

    float* ws     = (float*)d_ws;            // ~3.3 MB used
    float* F0     = ws;
    float* F1     = ws + NCELL;
    float* scale  = ws + 2 * NCELL;
    float* params = ws + 3 * NCELL;          // 512 floats
    int*   flags  = (int*)(ws + 3 * NCELL + 512);

    time2d_init<<<(NCELL + 255) / 256, 256, 0, stream>>>(
        vel, w, sx, sy, ry, F0, scale, params, flags);

    void* args[] = { (void*)&scale, (void*)&params, (void*)&F0, (void*)&F1,
                     (void*)&flags, (void*)&out };
    hipLaunchCooperativeKernel((void*)time2d_persist, dim3(16, 32), dim3(128),
                               args, 0, stream);
}

// Round 11
// 20361.702 us; speedup vs baseline: 1.0398x; 1.0398x over previous
//
#include <hip/hip_runtime.h>

typedef float f32x4 __attribute__((ext_vector_type(4)));

#define NXg   512
#define NYg   512
#define NTt   400
#define DIMg  520
#define NCELL (DIMg*DIMg)
#define DTc   0.001f
#define Hc    10.0f
#define FSTR  32            // flag stride in ints (128 B) — anti false sharing

#define C0f (-205.0f/72.0f)
#define C1f (8.0f/5.0f)
#define C2f (-1.0f/5.0f)
#define C3f (8.0f/315.0f)
#define C4f (-1.0f/560.0f)

// One-time per call: zero F0/F1 fields + flags, build scale[] (mask folded:
// 0 on the 4-wide pad ring), params: ints[0..2]=srcY,srcX,recY; [4+t]=w[t]*amp.
__global__ void time2d_init(const float* __restrict__ vel,
                            const float* __restrict__ w,
                            const int* __restrict__ sxp,
                            const int* __restrict__ syp,
                            const int* __restrict__ ryp,
                            float* __restrict__ F01,     // 2*NCELL
                            float* __restrict__ scale,
                            float* __restrict__ params,
                            int*   __restrict__ flags) {
    int idx = blockIdx.x * blockDim.x + threadIdx.x;
    if (idx < NCELL) {
        int y = idx / DIMg;
        int x = idx - y * DIMg;
        float s = 0.0f;
        if (y >= 4 && y < 516 && x >= 4 && x < 516) {
            // scale[y][x] = (vel[x-4][y-4]*DT)^2 / H^2   (transposed pad)
            float v = vel[(x - 4) * NYg + (y - 4)] * DTc;
            s = v * v / (Hc * Hc);
        }
        scale[idx] = s;
    }
    for (int i = idx; i < 2 * NCELL; i += gridDim.x * blockDim.x)
        F01[i] = 0.0f;
    if (idx < NTt) {
        const int sx = *sxp, sy = *syp;
        const float va = vel[sx * NYg + sy] * DTc;
        params[4 + idx] = w[idx] * (va * va);
    }
    if (idx < 512 * FSTR) flags[idx] = 0;
    if (idx == 0) {
        int* pi = (int*)params;
        pi[0] = *syp + 4;   // srcY
        pi[1] = *sxp + 4;   // srcX
        pi[2] = *ryp + 4;   // recY
    }
}

// Persistent dataflow kernel, GLOBAL<->GLOBAL (proven correct in round 10).
// Changes vs round 10 (poll path only):
//  - neighbor polls are relaxed atomic LOADS (no RMW -> no line ownership
//    ping-pong across 2048 pollers)
//  - flags padded to 1 per 128 B (no false sharing)
__launch_bounds__(128)
__global__ void time2d_persist(const float* __restrict__ scale,
                               const float* __restrict__ params,
                               float* __restrict__ F0,
                               float* __restrict__ F1,
                               int*   flags,
                               float* __restrict__ out)
{
    const int tid = threadIdx.x;
    const int bx = blockIdx.x, by = blockIdx.y;     // 16 x 32
    const int bid = by * 16 + bx;
    const int qc = tid & 7, r = tid >> 3;           // quad-col 0..7, row 0..15
    const int gxq = 4 + bx * 32 + qc * 4;
    const int gy  = 4 + by * 16 + r;
    const int myofs = gy * DIMg + gxq;

    const int* pi = (const int*)params;
    const int srcY = pi[0], srcX = pi[1], recY = pi[2];
    const float* wamp = params + 4;

    const f32x4 scq = *(const f32x4*)&scale[myofs];
    f32x4 prevq = (f32x4)0.0f;
    int srcJ = -1;
    if (gy == srcY && (unsigned)(srcX - gxq) < 4u) srcJ = srcX - gxq;
    const bool recRow = (gy == recY);

    // Poller assignment: tid0=W, tid1=E, tid2=N, tid3=S; missing -> self
    // (own flag == t at step t, passes immediately).
    int nbid = bid;
    if (tid == 0 && bx > 0)  nbid = bid - 1;
    if (tid == 1 && bx < 15) nbid = bid + 1;
    if (tid == 2 && by > 0)  nbid = bid - 16;
    if (tid == 3 && by < 31) nbid = bid + 16;
    int* nbflag = &flags[nbid * FSTR];

    for (int t = 0; t < NTt; ++t) {
        // 1. wait: neighbors completed >= t steps (relaxed LOAD polls)
        if (t > 0) {
            if (tid < 4)
                while (__hip_atomic_load(nbflag, __ATOMIC_RELAXED,
                                         __HIP_MEMORY_SCOPE_AGENT) < t)
                    __builtin_amdgcn_s_sleep(1);
            __syncthreads();
            __threadfence();          // acquire: invalidate caches
        }
        const float* __restrict__ Fs = (t & 1) ? F1 : F0;   // u(t)
        float*       __restrict__ Fd = (t & 1) ? F0 : F1;   // u(t+1)

        // 2. load window (plain vector loads; pad ring stays 0)
        f32x4 win[9];
        #pragma unroll
        for (int m = 0; m < 9; ++m)
            win[m] = *(const f32x4*)&Fs[myofs + (m - 4) * DIMg];
        const f32x4 lq = *(const f32x4*)&Fs[myofs - 4];
        const f32x4 rq = *(const f32x4*)&Fs[myofs + 4];

        // 3. compute
        float h[12];
        #pragma unroll
        for (int j = 0; j < 4; ++j) {
            h[j] = lq[j]; h[4 + j] = win[4][j]; h[8 + j] = rq[j];
        }
        f32x4 nv;
        const float wv = wamp[t];
        #pragma unroll
        for (int j = 0; j < 4; ++j) {
            const float ctr = h[4 + j];
            const float lap = 2.0f * C0f * ctr
              + C1f * (win[3][j] + win[5][j] + h[3 + j] + h[5 + j])
              + C2f * (win[2][j] + win[6][j] + h[2 + j] + h[6 + j])
              + C3f * (win[1][j] + win[7][j] + h[1 + j] + h[7 + j])
              + C4f * (win[0][j] + win[8][j] + h[0 + j] + h[8 + j]);
            float nvj = 2.0f * ctr - prevq[j] + scq[j] * lap;
            if (srcJ == j) nvj += wv;
            nv[j] = nvj;
        }
        prevq = win[4];

        // 4. store own quad + receiver row
        *(f32x4*)&Fd[myofs] = nv;
        if (recRow)
            *(f32x4*)&out[(size_t)t * NXg + (gxq - 4)] = nv;

        // 5. publish
        if (t < NTt - 1) {
            __threadfence();          // release: drain stores
            __syncthreads();
            if (tid == 0) atomicExch(&flags[bid * FSTR], t + 1);
        }
    }
}

extern "C" void kernel_launch(void* const* d_in, const int* in_sizes, int n_in,
                              void* d_out, int out_size, void* d_ws, size_t ws_size,
                              hipStream_t stream) {
    const float* vel = (const float*)d_in[0];
    const float* w   = (const float*)d_in[1];
    const int*   sx  = (const int*)d_in[2];
    const int*   sy  = (const int*)d_in[3];
    const int*   ry  = (const int*)d_in[4];
    float* out = (float*)d_out;

    float* ws     = (float*)d_ws;            // ~3.3 MB used
    float* F0     = ws;
    float* F1     = ws + NCELL;
    float* scale  = ws + 2 * NCELL;
    float* params = ws + 3 * NCELL;          // 512 floats
    int*   flags  = (int*)(ws + 3 * NCELL + 512);   // 512*FSTR ints = 64 KB

    time2d_init<<<(NCELL + 255) / 256, 256, 0, stream>>>(
        vel, w, sx, sy, ry, F0, scale, params, flags);

    void* args[] = { (void*)&scale, (void*)&params, (void*)&F0, (void*)&F1,
                     (void*)&flags, (void*)&out };
    hipLaunchCooperativeKernel((void*)time2d_persist, dim3(16, 32), dim3(128),
                               args, 0, stream);
}

// Round 12
// 1328.648 us; speedup vs baseline: 15.9358x; 15.3251x over previous
//
#include <hip/hip_runtime.h>

typedef float f32x4 __attribute__((ext_vector_type(4)));

#define NXg   512
#define NYg   512
#define NTt   400
#define DIMg  520
#define NCELL (DIMg*DIMg)
#define DTc   0.001f
#define Hc    10.0f

#define TILE_W 80          // x extent (own 32 + 2*24 halo, K<=6)
#define TILE_H 64          // y extent (own 16 + 2*24 halo)
#define TSTR   84          // padded LDS row stride (floats)
#define NQROW  20          // f32x4 quads per tile row
#define NQUADS (TILE_H * NQROW)   // 1280

#define C0f (-205.0f/72.0f)
#define C1f (8.0f/5.0f)
#define C2f (-1.0f/5.0f)
#define C3f (8.0f/315.0f)
#define C4f (-1.0f/560.0f)

// One-time per call: scale[] (mask folded in: 0 on pad ring), zero fields,
// params: ints [0..2]=srcY,srcX,recY ; floats [4+t]=w[t]*amp.
__global__ void time2d_init(const float* __restrict__ vel,
                            const float* __restrict__ w,
                            const int* __restrict__ sxp,
                            const int* __restrict__ syp,
                            const int* __restrict__ ryp,
                            float* __restrict__ scale,
                            float* __restrict__ fields,
                            float* __restrict__ params) {
    int idx = blockIdx.x * blockDim.x + threadIdx.x;
    if (idx < NCELL) {
        int y = idx / DIMg;
        int x = idx - y * DIMg;
        float s = 0.0f;
        if (y >= 4 && y < 516 && x >= 4 && x < 516) {
            // scale[y][x] = (vel[x-4][y-4]*DT)^2 / H^2   (transposed pad)
            float v = vel[(x - 4) * NYg + (y - 4)] * DTc;
            s = v * v / (Hc * Hc);
        }
        scale[idx] = s;
    }
    for (int i = idx; i < 4 * NCELL; i += gridDim.x * blockDim.x)
        fields[i] = 0.0f;
    if (idx < NTt) {
        const int sx = *sxp, sy = *syp;
        const float va = vel[sx * NYg + sy] * DTc;
        params[4 + idx] = w[idx] * (va * va);
    }
    if (idx == 0) {
        int* pi = (int*)params;
        pi[0] = *syp + 4;   // srcY
        pi[1] = *sxp + 4;   // srcX
        pi[2] = *ryp + 4;   // recY
    }
}

// One chunk = K steps (K<=6). 512 blocks (16x32) = 2 blocks/CU, 320 threads.
// Block owns a 32x16 interior tile, stages 80x64 into double-buffered LDS,
// runs K substeps with a SHRINKING compute region (rows [4k+4,60-4k), quads
// xc in [k+1,18-k]; both 4-aligned so each thread is all-in or all-out).
// Receiver-row values are kept in registers and written to `out` after the
// K-loop, so per-substep __syncthreads has no outstanding vmcnt work.
template<int K>
__launch_bounds__(320, 2)
__global__ void time2d_chunk(const float* __restrict__ Ps,
                             const float* __restrict__ Cs,
                             float* __restrict__ Pd,
                             float* __restrict__ Cd,
                             const float* __restrict__ scale,
                             const float* __restrict__ params,
                             float* __restrict__ out,
                             int t0)
{
    const int tid = threadIdx.x;
    const int bx = blockIdx.x, by = blockIdx.y;
    const int lx0 = bx * 32 - 20, ly0 = by * 16 - 20;   // tile origin (global)

    const int* pi = (const int*)params;
    const int srcY = pi[0], srcX = pi[1], recY = pi[2];

    __shared__ float lds[2][TILE_H * TSTR];

    // Stage cur tile (80x64) into LDS[0]; OOB -> 0 (pad semantics).
    #pragma unroll
    for (int ii = 0; ii < 4; ++ii) {
        const int pos = tid + 320 * ii;
        const int ty = pos / NQROW, txq = pos - ty * NQROW;
        const int gy = ly0 + ty, gx = lx0 + txq * 4;
        f32x4 v = (f32x4)0.0f;
        if ((unsigned)gy < 520u && (unsigned)gx < 517u)
            v = *(const f32x4*)&Cs[gy * DIMg + gx];
        *(f32x4*)&lds[0][ty * TSTR + txq * 4] = v;
    }

    // Thread mapping: 4x4 cells, rows [4,60) x 20 qcols -> 14x20 = 280 active.
    const int xc = tid % NQROW, pr = tid / NQROW;
    const bool active = (pr < 14);
    const int x4 = xc * 4;
    const int rb = 4 + pr * 4;                 // first of this thread's 4 rows
    const int gx0 = lx0 + x4;
    const bool ownedCol = (xc >= 6 && xc < 14);     // own local x [24,56)

    f32x4 scq[4], prevq[4], valq[4], recv[K];
    int srcI = -1, srcJ = 0;
    bool rec[4];
    int gyv[4];
    #pragma unroll
    for (int i = 0; i < 4; ++i) {
        const int gy = ly0 + rb + i;
        gyv[i] = gy;
        f32x4 s = (f32x4)0.0f, pv = (f32x4)0.0f;
        if (active && (unsigned)gy < 520u && (unsigned)gx0 < 517u) {
            s  = *(const f32x4*)&scale[gy * DIMg + gx0];
            pv = *(const f32x4*)&Ps[gy * DIMg + gx0];
        }
        scq[i] = s; prevq[i] = pv;
        #pragma unroll
        for (int j = 0; j < 4; ++j)
            if (gy == srcY && gx0 + j == srcX) { srcI = i; srcJ = j; }
        const bool ownRow = ((unsigned)(rb + i - 24) < 16u);  // own local y [24,40)
        rec[i] = ownedCol && ownRow && (gy == recY);
    }

    float injs[K];
    #pragma unroll
    for (int k = 0; k < K; ++k)
        injs[k] = (srcI >= 0) ? params[4 + t0 + k] : 0.0f;

    __syncthreads();   // staging loads drain here, once

    int p = 0;
    #pragma unroll
    for (int k = 0; k < K; ++k) {
        const float* cur = lds[p];
        float* nxt = lds[p ^ 1];
        // Shrinking compute region: rows [4k+4, 60-4k), quads xc [k+1, 18-k].
        const bool docomp = active
            && (rb >= 4 * k + 4) && (rb <= 56 - 4 * k)
            && (xc >= k + 1) && (xc <= 18 - k);
        if (docomp) {
            f32x4 win[12];
            #pragma unroll
            for (int m = 0; m < 12; ++m)
                win[m] = *(const f32x4*)&cur[(rb - 4 + m) * TSTR + x4];
            #pragma unroll
            for (int i = 0; i < 4; ++i) {
                const int y = rb + i;
                const f32x4 lq = *(const f32x4*)&cur[y * TSTR + x4 - 4];
                const f32x4 rq = *(const f32x4*)&cur[y * TSTR + x4 + 4];
                float h[12];
                #pragma unroll
                for (int j = 0; j < 4; ++j) {
                    h[j] = lq[j]; h[4 + j] = win[4 + i][j]; h[8 + j] = rq[j];
                }
                f32x4 nv;
                #pragma unroll
                for (int j = 0; j < 4; ++j) {
                    const float ctr = h[4 + j];
                    const float lap = 2.0f * C0f * ctr
                      + C1f * (win[3 + i][j] + win[5 + i][j] + h[3 + j] + h[5 + j])
                      + C2f * (win[2 + i][j] + win[6 + i][j] + h[2 + j] + h[6 + j])
                      + C3f * (win[1 + i][j] + win[7 + i][j] + h[1 + j] + h[7 + j])
                      + C4f * (win[0 + i][j] + win[8 + i][j] + h[0 + j] + h[8 + j]);
                    float nvj = 2.0f * ctr - prevq[i][j] + scq[i][j] * lap;
                    if (srcI == i && srcJ == j) nvj += injs[k];
                    nv[j] = nvj;
                    prevq[i][j] = ctr;
                }
                *(f32x4*)&nxt[y * TSTR + x4] = nv;
                valq[i] = nv;
                if (rec[i]) recv[k] = nv;   // defer global write past the loop
            }
        }
        if (k < K - 1) __syncthreads();
        p ^= 1;
    }

    // Deferred receiver-row writes (own cells valid at every substep).
    if (rec[0] | rec[1] | rec[2] | rec[3]) {
        #pragma unroll
        for (int k = 0; k < K; ++k)
            *(f32x4*)&out[(size_t)(t0 + k) * NXg + (gx0 - 4)] = recv[k];
    }

    // Write back owned 32x16 region of the last two time levels.
    if (ownedCol) {
        #pragma unroll
        for (int i = 0; i < 4; ++i) {
            if ((unsigned)(rb + i - 24) < 16u) {
                const size_t g = (size_t)gyv[i] * DIMg + gx0;
                *(f32x4*)&Pd[g] = prevq[i];   // u(t0+K-1)
                *(f32x4*)&Cd[g] = valq[i];    // u(t0+K)
            }
        }
    }
}

extern "C" void kernel_launch(void* const* d_in, const int* in_sizes, int n_in,
                              void* d_out, int out_size, void* d_ws, size_t ws_size,
                              hipStream_t stream) {
    const float* vel = (const float*)d_in[0];
    const float* w   = (const float*)d_in[1];
    const int*   sx  = (const int*)d_in[2];
    const int*   sy  = (const int*)d_in[3];
    const int*   ry  = (const int*)d_in[4];
    float* out = (float*)d_out;

    float* ws     = (float*)d_ws;     // needs ~5.41 MB
    float* scale  = ws;
    float* params = ws + NCELL;
    float* fld    = params + 512;
    float* P[2]   = { fld,           fld + 2 * NCELL };
    float* C[2]   = { fld + NCELL,   fld + 3 * NCELL };

    time2d_init<<<(NCELL + 255) / 256, 256, 0, stream>>>(
        vel, w, sx, sy, ry, scale, fld, params);

    dim3 grid(16, 32);   // 512 blocks, own 32x16, 2 blocks/CU
    // 66 chunks of K=6 (t=0..395) + 1 chunk of K=4 (t=396..399)
    for (int c = 0; c < 66; ++c) {
        const int s = c & 1, d = s ^ 1;
        time2d_chunk<6><<<grid, 320, 0, stream>>>(P[s], C[s], P[d], C[d],
                                                  scale, params, out, c * 6);
    }
    {
        const int s = 66 & 1, d = s ^ 1;
        time2d_chunk<4><<<grid, 320, 0, stream>>>(P[s], C[s], P[d], C[d],
                                                  scale, params, out, 396);
    }
}